// Round 20
// baseline (931.597 us; speedup 1.0000x reference)
//
#include <hip/hip_runtime.h>
#include <hip/hip_bf16.h>

#define NPAD 16640
#define TOK  16385
#define CDIM 512
#define NHEAD 8
#define DHEAD 64
#define NLAND 256
#define LFAC  65
#define PAD0  255
#define NCHUNK 65     // 256-row chunks
#define CGRP 2        // chunks per block in a3v
#define NCG 33        // ceil(65/2)

typedef __attribute__((ext_vector_type(8))) short sh8;
typedef __attribute__((ext_vector_type(4))) float f4;

__device__ __forceinline__ float wave_sum(float v){
  #pragma unroll
  for(int o=32;o;o>>=1) v += __shfl_xor(v,o);
  return v;
}
__device__ __forceinline__ float wave_max(float v){
  #pragma unroll
  for(int o=32;o;o>>=1) v = fmaxf(v, __shfl_xor(v,o));
  return v;
}

__device__ __forceinline__ unsigned bfbits(float x){
  unsigned u = __float_as_uint(x);
  return (u + 0x7fffu + ((u >> 16) & 1u)) >> 16;
}
__device__ __forceinline__ float bf2f(short s){
  return __uint_as_float(((unsigned)(unsigned short)s) << 16);
}
__device__ __forceinline__ sh8 pack8f(float4 a, float4 b){
  sh8 r;
  r[0]=(short)bfbits(a.x); r[1]=(short)bfbits(a.y); r[2]=(short)bfbits(a.z); r[3]=(short)bfbits(a.w);
  r[4]=(short)bfbits(b.x); r[5]=(short)bfbits(b.y); r[6]=(short)bfbits(b.z); r[7]=(short)bfbits(b.w);
  return r;
}
#define MFMA16(a,b,c) __builtin_amdgcn_mfma_f32_16x16x32_bf16(a,b,c,0,0,0)

__device__ __forceinline__ void gload16(const void* g, void* l){
  __builtin_amdgcn_global_load_lds(
      (const __attribute__((address_space(1))) void*)g,
      (__attribute__((address_space(3))) void*)l, 16, 0, 0);
}

// lgkm-only barrier: drains LDS ops but leaves global prefetch (vmcnt) in flight
#define BAR_LGKM() do{ \
  asm volatile("s_waitcnt lgkmcnt(0)" ::: "memory"); \
  __builtin_amdgcn_s_barrier(); \
  __builtin_amdgcn_sched_barrier(0); \
}while(0)

// ---------------- row copy (cls token) ----------------
__global__ void k_copyrow(float* dst, const float* __restrict__ src){
  dst[threadIdx.x] = src[threadIdx.x];
}

// ---------------- f32 -> bf16 convert ----------------
__global__ __launch_bounds__(256) void k_f2b(const float* __restrict__ in,
    short* __restrict__ out, int n8){
  int i = blockIdx.x*256 + threadIdx.x;
  if(i < n8){
    float4 a = *(const float4*)(in + (size_t)i*8);
    float4 b = *(const float4*)(in + (size_t)i*8 + 4);
    *(sh8*)(out + (size_t)i*8) = pack8f(a, b);
  }
}

// ---------------- layernorm + front pad -> bf16 ----------------
__global__ __launch_bounds__(256) void k_ln_pad(const float* __restrict__ A,
    const float* __restrict__ g, const float* __restrict__ b, short* __restrict__ B){
  int w = threadIdx.x >> 6, lane = threadIdx.x & 63;
  int row = blockIdx.x*4 + w;
  short* out = B + (size_t)row*CDIM;
  int c = lane*8;
  if(row < PAD0){
    sh8 z = {0,0,0,0,0,0,0,0};
    *(sh8*)(out + c) = z;
    return;
  }
  const float* x = A + (size_t)(row-PAD0)*CDIM;
  float4 v0 = *(const float4*)(x + c);
  float4 v1 = *(const float4*)(x + c + 4);
  float xs[8] = {v0.x,v0.y,v0.z,v0.w,v1.x,v1.y,v1.z,v1.w};
  float s = 0;
  #pragma unroll
  for(int i=0;i<8;i++) s += xs[i];
  s = wave_sum(s);
  float mu = s * (1.f/512.f);
  float vs = 0;
  #pragma unroll
  for(int i=0;i<8;i++){ float d = xs[i]-mu; vs += d*d; }
  vs = wave_sum(vs) * (1.f/512.f);
  float rs = rsqrtf(vs + 1e-5f);
  float4 g0 = *(const float4*)(g + c); float4 g1 = *(const float4*)(g + c + 4);
  float4 b0 = *(const float4*)(b + c); float4 b1 = *(const float4*)(b + c + 4);
  float gg[8] = {g0.x,g0.y,g0.z,g0.w,g1.x,g1.y,g1.z,g1.w};
  float bb[8] = {b0.x,b0.y,b0.z,b0.w,b1.x,b1.y,b1.z,b1.w};
  sh8 o;
  #pragma unroll
  for(int i=0;i<8;i++) o[i] = (short)bfbits((xs[i]-mu)*rs*gg[i] + bb[i]);
  *(sh8*)(out + c) = o;
}

// ---------------- gload-staged MFMA GEMM with counted-vmcnt pipeline (T4) --------
// C[M,N] = A[M,K] @ WT[N,K]^T, A/WT bf16. 128x128 tile, BK=32, double-buffered.
// Barriers never drain the in-flight next-tile prefetch: vmcnt(4) waits only for
// the current tile's 4 loads; post-MFMA barrier is lgkm-only.
template<int MODE>
__global__ __launch_bounds__(256) void k_gemm_g(const short* __restrict__ A, int lda,
    const short* __restrict__ WT, int K, const float* __restrict__ bias,
    void* out0v, void* out1v, void* out2v, int M){
  __shared__ short As[2][128*32];
  __shared__ short Bs[2][128*32];
  int t = threadIdx.x, lane = t & 63, wv = t >> 6, g = lane >> 4, l15 = lane & 15;
  int nwg = gridDim.x * gridDim.y;
  int orig = blockIdx.y * gridDim.x + blockIdx.x;
  int qc = nwg >> 3, rc = nwg & 7, xcd = orig & 7, loc = orig >> 3;
  int wgid = (xcd < rc ? xcd*(qc+1) : rc*(qc+1) + (xcd - rc)*qc) + loc;
  int row0 = (wgid / gridDim.x) * 128, n0 = (wgid % gridDim.x) * 128;
  int wm = (wv>>1)*64, wn = (wv&1)*64;
  int mq = lane >> 2, slot = lane & 3;

  auto stage = [&](int buf, int k0){
    #pragma unroll
    for(int c=0;c<2;c++){
      int m = wv*32 + c*16 + mq;
      int swz = (((m&3) ^ ((m>>2)&3)) << 4);
      int gr = row0 + m; if(gr >= M) gr = M-1;
      const char* srcA = (const char*)(A + (size_t)gr*lda + k0) + ((slot*16) ^ swz);
      gload16(srcA, (char*)As[buf] + wv*2048 + c*1024);
      const char* srcB = (const char*)(WT + (size_t)(n0+m)*K + k0) + ((slot*16) ^ swz);
      gload16(srcB, (char*)Bs[buf] + wv*2048 + c*1024);
    }
  };

  f4 acc[4][4] = {};
  int nk = K >> 5;
  stage(0, 0);                       // 4 vm ops/wave in flight
  int cur = 0;
  for(int i=0; i<nk; i++){
    if(i+1 < nk){
      stage(cur^1, (i+1) << 5);      // +4 vm ops (8 outstanding)
      asm volatile("s_waitcnt vmcnt(4)" ::: "memory");  // oldest 4 (cur) landed
    } else {
      asm volatile("s_waitcnt vmcnt(0)" ::: "memory");  // final tile: drain all
    }
    __builtin_amdgcn_s_barrier();    // cur tile visible to all waves
    __builtin_amdgcn_sched_barrier(0);
    sh8 af[4], bf[4];
    #pragma unroll
    for(int mt=0; mt<4; mt++){
      int r = wm + mt*16 + l15;
      af[mt] = *(sh8*)((char*)As[cur] + r*64 + ((g*16) ^ (((r&3)^((r>>2)&3))<<4)));
    }
    #pragma unroll
    for(int nt=0; nt<4; nt++){
      int r = wn + nt*16 + l15;
      bf[nt] = *(sh8*)((char*)Bs[cur] + r*64 + ((g*16) ^ (((r&3)^((r>>2)&3))<<4)));
    }
    #pragma unroll
    for(int mt=0; mt<4; mt++)
      #pragma unroll
      for(int nt=0; nt<4; nt++)
        acc[mt][nt] = MFMA16(af[mt], bf[nt], acc[mt][nt]);
    BAR_LGKM();                      // LDS reads done before buffer reuse; vm stays live
    cur ^= 1;
  }
  #pragma unroll
  for(int mt=0; mt<4; mt++){
    #pragma unroll
    for(int r=0; r<4; r++){
      int gm = row0 + wm + mt*16 + g*4 + r;
      if(gm >= M) continue;
      #pragma unroll
      for(int nt=0; nt<4; nt++){
        int gn = n0 + wn + nt*16 + l15;
        float v = acc[mt][nt][r];
        if(MODE == 0){
          v += bias[gn];
          ((float*)out0v)[(size_t)gm*CDIM + gn] = v > 0.f ? v : 0.f;
        } else if(MODE == 1){
          int p = gn >> 9, rr = gn & 511;
          int hh = rr >> 6, dd = rr & 63;
          if(p == 0) v *= 0.125f;
          short* dst = (p==0) ? (short*)out0v : (p==1 ? (short*)out1v : (short*)out2v);
          dst[((size_t)hh*NPAD + gm)*DHEAD + dd] = (short)bfbits(v);
        } else {
          ((float*)out0v)[(size_t)gm*CDIM + gn] += v + bias[gn];
        }
      }
    }
  }
}

// ---------------- landmark means, Q and K in one dispatch ----------------
__global__ void k_landmark2(const short* __restrict__ Qb, const short* __restrict__ Kb,
    float* __restrict__ ql, float* __restrict__ kl){
  int bidx = blockIdx.x;
  int sel = bidx >> 11;
  int loc = bidx & 2047;
  int h = loc >> 8, m = loc & 255, d = threadIdx.x;
  const short* src = (sel ? Kb : Qb) + ((size_t)h*NPAD + (size_t)m*LFAC)*DHEAD + d;
  float s = 0;
  for(int j=0;j<LFAC;j++) s += bf2f(src[(size_t)j*DHEAD]);
  (sel ? kl : ql)[(size_t)loc*DHEAD + d] = s * (1.f/LFAC);
}

// ---------------- a2 = softmax(ql @ kl^T), MFMA ----------------
__global__ __launch_bounds__(256) void k_a2_mfma(const float* __restrict__ ql,
    const float* __restrict__ kl, float* __restrict__ a2, short* __restrict__ a2bf){
  __shared__ short klL[256*64];   // [n][d] bf16, 128B rows, XOR swizzle
  int q = blockIdx.x, h = blockIdx.y;
  int t = threadIdx.x, lane = t & 63, wv = t >> 6, g = lane >> 4, l15 = lane & 15;
  const float* qlh = ql + (size_t)h*NLAND*DHEAD;
  const float* klh = kl + (size_t)h*NLAND*DHEAD;
  #pragma unroll
  for(int i=0;i<8;i++){
    int gi = t + i*256;
    int n = gi >> 3, db = (gi & 7)*8;
    float4 a = *(const float4*)(klh + (size_t)n*DHEAD + db);
    float4 b = *(const float4*)(klh + (size_t)n*DHEAD + db + 4);
    *(sh8*)((char*)klL + n*128 + ((db*2) ^ ((n&7)<<4))) = pack8f(a, b);
  }
  __syncthreads();
  int row0 = q*64 + wv*16;
  sh8 aQ[2];
  #pragma unroll
  for(int kk=0; kk<2; kk++){
    const float* p = qlh + (size_t)(row0 + l15)*DHEAD + kk*32 + g*8;
    aQ[kk] = pack8f(*(const float4*)p, *(const float4*)(p+4));
  }
  f4 acc[16];
  #pragma unroll
  for(int nt=0; nt<16; nt++){
    f4 s = {};
    #pragma unroll
    for(int kk=0; kk<2; kk++){
      int n = nt*16 + l15;
      sh8 b = *(sh8*)((char*)klL + n*128 + ((kk*64 + g*16) ^ ((n&7)<<4)));
      s = MFMA16(aQ[kk], b, s);
    }
    acc[nt] = s;
  }
  float den[4] = {0,0,0,0};
  #pragma unroll
  for(int nt=0; nt<16; nt++)
    #pragma unroll
    for(int r=0; r<4; r++){
      float e = __expf(acc[nt][r]);
      acc[nt][r] = e;
      den[r] += e;
    }
  #pragma unroll
  for(int r=0; r<4; r++){
    float d_ = den[r];
    d_ += __shfl_xor(d_,1); d_ += __shfl_xor(d_,2);
    d_ += __shfl_xor(d_,4); d_ += __shfl_xor(d_,8);
    den[r] = 1.f/d_;
  }
  #pragma unroll
  for(int nt=0; nt<16; nt++)
    #pragma unroll
    for(int r=0; r<4; r++){
      int row = row0 + g*4 + r;
      int col = nt*16 + l15;
      float v = acc[nt][r]*den[r];
      size_t idx = ((size_t)h*NLAND + row)*NLAND + col;
      a2[idx] = v;
      a2bf[idx] = (short)bfbits(v);
    }
}

// ---------------- pinv init ----------------
__global__ void k_colmax(const float* __restrict__ a2, float* __restrict__ hmax){
  __shared__ float red[4];
  int h = blockIdx.x, t = threadIdx.x;
  const float* p = a2 + (size_t)h*65536 + t;
  float s = 0;
  for(int m=0;m<256;m++) s += p[(size_t)m*256];
  float mx = wave_max(s);
  if((t & 63) == 0) red[t>>6] = mx;
  __syncthreads();
  if(t == 0) hmax[h] = fmaxf(fmaxf(red[0],red[1]), fmaxf(red[2],red[3]));
}
// z0 (bf16) = a2^T / max(hmax)
__global__ void k_zinit(const float* __restrict__ a2, const float* __restrict__ hmax,
                        short* __restrict__ z){
  int h = blockIdx.y;
  int idx = blockIdx.x*256 + threadIdx.x;
  int m = idx >> 8, j = idx & 255;
  float mx = hmax[0];
  #pragma unroll
  for(int i=1;i<8;i++) mx = fmaxf(mx, hmax[i]);
  z[(size_t)h*65536 + idx] = (short)bfbits(a2[(size_t)h*65536 + (size_t)j*256 + m] / mx);
}

// ---------------- batched MFMA pinv GEMM, bf16 I/O ----------------
template<int TRANS, int F32OUT>
__global__ __launch_bounds__(256) void k_pgemm(const short* __restrict__ A,
    const short* __restrict__ B, short* __restrict__ C, float* __restrict__ Cf,
    float alpha, float beta){
  __shared__ short As[64*32];
  __shared__ short Bs[64*32];
  int bh = blockIdx.z;
  const short* Ah = A + (size_t)bh*65536;
  const short* Bh = B + (size_t)bh*65536;
  int m0 = blockIdx.y*64, n0 = blockIdx.x*64;
  int t = threadIdx.x, lane = t & 63, wv = t >> 6, g = lane >> 4, l15 = lane & 15;
  f4 acc[4] = {};
  for(int k0=0; k0<256; k0+=32){
    {
      int m = t >> 2, kb = (t & 3)*8;
      sh8 av = *(const sh8*)(Ah + (size_t)(m0+m)*256 + k0 + kb);
      int swz = (((m&3)^((m>>2)&3))<<4);
      *(sh8*)((char*)As + m*64 + ((kb*2)^swz)) = av;
    }
    {
      int kr = t >> 3, nb = (t & 7)*8;
      sh8 bv = *(const sh8*)(Bh + (size_t)(k0+kr)*256 + n0 + nb);
      #pragma unroll
      for(int e=0;e<8;e++){
        int n = nb + e;
        short sv = bv[e];
        if(TRANS){
          float f = ((k0+kr == n0+n) ? alpha : 0.f) - bf2f(sv);
          sv = (short)bfbits(f);
        }
        int swz = (((n&3)^((n>>2)&3))<<4);
        *(short*)((char*)Bs + n*64 + ((kr*2)^swz)) = sv;
      }
    }
    __syncthreads();
    int rm = wv*16 + l15;
    sh8 af = *(sh8*)((char*)As + rm*64 + ((g*16) ^ (((rm&3)^((rm>>2)&3))<<4)));
    #pragma unroll
    for(int nt=0; nt<4; nt++){
      int n = nt*16 + l15;
      sh8 bf = *(sh8*)((char*)Bs + n*64 + ((g*16) ^ (((n&3)^((n>>2)&3))<<4)));
      acc[nt] = MFMA16(af, bf, acc[nt]);
    }
    __syncthreads();
  }
  size_t hoff = (size_t)bh*65536;
  #pragma unroll
  for(int nt=0; nt<4; nt++)
    #pragma unroll
    for(int r=0; r<4; r++){
      size_t idx = hoff + (size_t)(m0 + wv*16 + g*4 + r)*256 + n0 + nt*16 + l15;
      float v = acc[nt][r]*beta;
      if(F32OUT) Cf[idx] = v;
      else       C[idx] = (short)bfbits(v);
    }
}

// ---------------- batched f32 GEMM 64x64 tile (w2^T only) ----------------
template<int TRANS, int OUTT>
__global__ __launch_bounds__(256) void k_sgemm2(const float* __restrict__ A,
    const float* __restrict__ B, float* __restrict__ C,
    int M, int N, int K, long sA, long sB, long sC, float alpha, float beta){
  __shared__ float As[32][68];
  __shared__ float Bs[32][68];
  int bh = blockIdx.z;
  const float* Ah = A + (size_t)bh*sA;
  const float* Bh = B + (size_t)bh*sB;
  float* Ch = C + (size_t)bh*sC;
  int m0 = blockIdx.y*64, n0 = blockIdx.x*64;
  int t = threadIdx.x, tx = t & 15, ty = t >> 4;
  float acc[4][4] = {};
  for(int k0=0; k0<K; k0+=32){
    #pragma unroll
    for(int u=0; u<2; u++){
      int idx = t + u*256;
      int r = idx >> 3, cb = (idx & 7) * 4;
      float4 va = *(const float4*)(Ah + (size_t)(m0+r)*K + k0 + cb);
      As[cb+0][r]=va.x; As[cb+1][r]=va.y; As[cb+2][r]=va.z; As[cb+3][r]=va.w;
      int kr = idx >> 4, nb = (idx & 15) * 4;
      float4 w = *(const float4*)(Bh + (size_t)(k0+kr)*N + n0 + nb);
      if(TRANS){
        int gk = k0 + kr;
        w.x = ((gk==n0+nb+0)?alpha:0.f) - w.x;
        w.y = ((gk==n0+nb+1)?alpha:0.f) - w.y;
        w.z = ((gk==n0+nb+2)?alpha:0.f) - w.z;
        w.w = ((gk==n0+nb+3)?alpha:0.f) - w.w;
      }
      *(float4*)&Bs[kr][nb] = w;
    }
    __syncthreads();
    #pragma unroll
    for(int k=0;k<32;k++){
      float a[4], b[4];
      *(float4*)a = *(const float4*)&As[k][ty*4];
      *(float4*)b = *(const float4*)&Bs[k][tx*4];
      #pragma unroll
      for(int i=0;i<4;i++)
        #pragma unroll
        for(int j=0;j<4;j++) acc[i][j] += a[i]*b[j];
    }
    __syncthreads();
  }
  #pragma unroll
  for(int i=0;i<4;i++){
    #pragma unroll
    for(int j=0;j<4;j++){
      int gm = m0 + ty*4 + i, gn = n0 + tx*4 + j;
      float v = acc[i][j] * beta;
      if(OUTT) Ch[(size_t)gn*M + gm] = v;
      else     Ch[(size_t)gm*N + gn] = v;
    }
  }
}

// ---------------- MFMA flash a1 (Q bf16, F out bf16), per-wave P ----------------
__global__ __launch_bounds__(256) void k_a1_mfma(const short* __restrict__ Qb,
    const float* __restrict__ kl, const float* __restrict__ w2t, short* __restrict__ F){
  __shared__ short klL[128*64];
  __shared__ short w2L[64*128];
  __shared__ short pL[4][16*128];
  int h = blockIdx.y, n0 = blockIdx.x*128;
  int t = threadIdx.x, lane = t & 63, wv = t >> 6, g = lane >> 4, l15 = lane & 15;
  const float* klh = kl + (size_t)h*NLAND*DHEAD;
  const float* w2h = w2t + (size_t)h*DHEAD*NLAND;
  const short* qbase = Qb + (size_t)h*NPAD*DHEAD;
  sh8 aQ[2][2];
  #pragma unroll
  for(int st=0; st<2; st++)
    #pragma unroll
    for(int kk=0; kk<2; kk++)
      aQ[st][kk] = *(const sh8*)(qbase +
          (size_t)(n0 + wv*32 + st*16 + l15)*DHEAD + kk*32 + g*8);
  f4 accO[2][4] = {};
  float den[2][4] = {};
  short* pw = pL[wv];
  for(int half=0; half<2; half++){
    __syncthreads();
    #pragma unroll
    for(int it=0; it<4; it++){
      int gi = t + it*256;
      int m = gi >> 3, db = (gi & 7) * 8;
      const float* p = klh + (size_t)(half*128 + m)*DHEAD + db;
      *(sh8*)((char*)klL + m*128 + ((db*2) ^ ((m&7)<<4))) =
          pack8f(*(const float4*)p, *(const float4*)(p+4));
      int d = gi >> 4, mb = (gi & 15) * 8;
      const float* p2 = w2h + (size_t)d*NLAND + half*128 + mb;
      *(sh8*)((char*)w2L + d*256 + ((mb*2) ^ ((d&7)<<4))) =
          pack8f(*(const float4*)p2, *(const float4*)(p2+4));
    }
    __syncthreads();
    #pragma unroll
    for(int st=0; st<2; st++){
      #pragma unroll
      for(int mt=0; mt<8; mt++){
        f4 s = {};
        #pragma unroll
        for(int kk=0; kk<2; kk++){
          int m = mt*16 + l15;
          sh8 b = *(sh8*)((char*)klL + m*128 + ((kk*64 + g*16) ^ ((m&7)<<4)));
          s = MFMA16(aQ[st][kk], b, s);
        }
        #pragma unroll
        for(int r=0; r<4; r++){
          float e = __expf(s[r]);
          den[st][r] += e;
          int n = g*4 + r;
          *(short*)((char*)pw + n*256 + (((mt*16+l15)*2) ^ ((n&7)<<4))) = (short)bfbits(e);
        }
      }
      #pragma unroll
      for(int ks=0; ks<4; ks++){
        sh8 aP = *(sh8*)((char*)pw + l15*256 + ((ks*64 + g*16) ^ ((l15&7)<<4)));
        #pragma unroll
        for(int dt=0; dt<4; dt++){
          int d = dt*16 + l15;
          sh8 bW = *(sh8*)((char*)w2L + d*256 + ((ks*64 + g*16) ^ ((d&7)<<4)));
          accO[st][dt] = MFMA16(aP, bW, accO[st][dt]);
        }
      }
    }
  }
  #pragma unroll
  for(int st=0; st<2; st++)
    #pragma unroll
    for(int r=0; r<4; r++){
      float d_ = den[st][r];
      d_ += __shfl_xor(d_,1); d_ += __shfl_xor(d_,2);
      d_ += __shfl_xor(d_,4); d_ += __shfl_xor(d_,8);
      den[st][r] = 1.f/d_;
    }
  #pragma unroll
  for(int st=0; st<2; st++)
    #pragma unroll
    for(int dt=0; dt<4; dt++)
      #pragma unroll
      for(int r=0; r<4; r++){
        int row = n0 + wv*32 + st*16 + g*4 + r;
        F[(size_t)row*CDIM + h*DHEAD + dt*16 + l15] =
            (short)bfbits(accO[st][dt][r]*den[st][r]);
      }
}

// ---------------- MFMA flash a3v: 8 waves, lgkm-only barriers, reg prefetch ------
__global__ __launch_bounds__(512) void k_a3v_mfma(const float* __restrict__ ql,
    const short* __restrict__ Kb, const short* __restrict__ Vb,
    float* __restrict__ numP, float* __restrict__ denP){
  __shared__ short kL[128*64];
  __shared__ short vL[64*128];
  __shared__ short pL[8][16*128];
  int h = blockIdx.x, cg = blockIdx.y;
  int t = threadIdx.x, lane = t & 63, wv = t >> 6, g = lane >> 4, l15 = lane & 15;
  int r0 = (wv & 3)*64 + (wv >> 2)*32;
  const float* qlh = ql + (size_t)h*NLAND*DHEAD;
  sh8 aQ[2][2];
  #pragma unroll
  for(int st=0; st<2; st++)
    #pragma unroll
    for(int kk=0; kk<2; kk++){
      const float* p = qlh + (size_t)(r0 + st*16 + l15)*DHEAD + kk*32 + g*8;
      aQ[st][kk] = pack8f(*(const float4*)p, *(const float4*)(p+4));
    }
  f4 accO[2][4] = {};
  float den[2][4] = {};
  short* pw = pL[wv];

  int km[2], kdb[2];
  #pragma unroll
  for(int it=0; it<2; it++){
    int gi = t + it*512;
    km[it] = gi >> 3; kdb[it] = (gi & 7) * 8;
  }
  int vmp = (t & 63)*2, vdg = (t >> 6)*8;

  sh8 kreg[2], vreg[2];
  auto ldregs = [&](int ph){
    int c = cg*CGRP + (ph >> 1), half = ph & 1;
    const short* Kh = Kb + ((size_t)h*NPAD + (size_t)c*256 + half*128)*DHEAD;
    const short* Vh = Vb + ((size_t)h*NPAD + (size_t)c*256 + half*128)*DHEAD;
    #pragma unroll
    for(int it=0; it<2; it++)
      kreg[it] = *(const sh8*)(Kh + (size_t)km[it]*DHEAD + kdb[it]);
    vreg[0] = *(const sh8*)(Vh + (size_t)vmp*DHEAD + vdg);
    vreg[1] = *(const sh8*)(Vh + (size_t)(vmp+1)*DHEAD + vdg);
  };

  int nph = 2*CGRP;
  if(cg*CGRP + ((nph-1) >> 1) >= NCHUNK) nph = 2;
  ldregs(0);
  for(int ph=0; ph<nph; ph++){
    BAR_LGKM();
    #pragma unroll
    for(int it=0; it<2; it++)
      *(sh8*)((char*)kL + km[it]*128 + ((kdb[it]*2) ^ ((km[it]&7)<<4))) = kreg[it];
    {
      sh8 v0 = vreg[0], v1 = vreg[1];
      #pragma unroll
      for(int i=0;i<8;i++){
        int d = vdg + i;
        unsigned pk = ((unsigned)(unsigned short)v0[i]) |
                      (((unsigned)(unsigned short)v1[i]) << 16);
        *(unsigned*)((char*)vL + d*256 + ((vmp*2) ^ ((d&7)<<4))) = pk;
      }
    }
    if(ph+1 < nph) ldregs(ph+1);
    BAR_LGKM();
    #pragma unroll
    for(int st=0; st<2; st++){
      #pragma unroll
      for(int mt=0; mt<8; mt++){
        f4 s = {};
        #pragma unroll
        for(int kk=0; kk<2; kk++){
          int m = mt*16 + l15;
          sh8 b = *(sh8*)((char*)kL + m*128 + ((kk*64 + g*16) ^ ((m&7)<<4)));
          s = MFMA16(aQ[st][kk], b, s);
        }
        #pragma unroll
        for(int r=0; r<4; r++){
          float e = __expf(s[r]);
          den[st][r] += e;
          int n = g*4 + r;
          *(short*)((char*)pw + n*256 + (((mt*16+l15)*2) ^ ((n&7)<<4))) = (short)bfbits(e);
        }
      }
      #pragma unroll
      for(int ks=0; ks<4; ks++){
        sh8 aP = *(sh8*)((char*)pw + l15*256 + ((ks*64 + g*16) ^ ((l15&7)<<4)));
        #pragma unroll
        for(int dt=0; dt<4; dt++){
          int d = dt*16 + l15;
          sh8 bV = *(sh8*)((char*)vL + d*256 + ((ks*64 + g*16) ^ ((d&7)<<4)));
          accO[st][dt] = MFMA16(aP, bV, accO[st][dt]);
        }
      }
    }
  }
  #pragma unroll
  for(int st=0; st<2; st++)
    #pragma unroll
    for(int r=0; r<4; r++){
      float d_ = den[st][r];
      d_ += __shfl_xor(d_,1); d_ += __shfl_xor(d_,2);
      d_ += __shfl_xor(d_,4); d_ += __shfl_xor(d_,8);
      den[st][r] = d_;
    }
  size_t base = ((size_t)h*NCG + cg)*NLAND;
  #pragma unroll
  for(int st=0; st<2; st++){
    #pragma unroll
    for(int r=0; r<4; r++){
      int row = r0 + st*16 + g*4 + r;
      if(l15 == 0) denP[base + row] = den[st][r];
      #pragma unroll
      for(int dt=0; dt<4; dt++)
        numP[(base + row)*DHEAD + dt*16 + l15] = accO[st][dt][r];
    }
  }
}

__global__ void k_a3v_comb(const float* __restrict__ numP, const float* __restrict__ denP,
                           float* __restrict__ a3v){
  int bidx = blockIdx.x;
  int h = bidx >> 8, m = bidx & 255;
  int d = threadIdx.x;
  float s = 0.f, den = 0.f;
  for(int c=0;c<NCG;c++){
    s += numP[(((size_t)h*NCG + c)*NLAND + m)*DHEAD + d];
    den += denP[((size_t)h*NCG + c)*NLAND + m];
  }
  a3v[((size_t)h*NLAND + m)*DHEAD + d] = s / den;
}

// ---------------- residual depthwise conv (k=33), register-FIR ----------------
__global__ __launch_bounds__(256) void k_resconv(const short* __restrict__ Vb,
    const float* __restrict__ rw, short* __restrict__ F){
  __shared__ float vs[96][64];
  int n0 = blockIdx.x*64, h = blockIdx.y;
  int t = threadIdx.x;
  const short* vh = Vb + (size_t)h*NPAD*DHEAD;
  #pragma unroll
  for(int i=0;i<3;i++){
    int idx = t + i*256;
    int r = idx >> 3, dg = (idx & 7)*8;
    int n = n0 - 16 + r;
    sh8 v = {0,0,0,0,0,0,0,0};
    if(n>=0 && n<NPAD) v = *(const sh8*)(vh + (size_t)n*DHEAD + dg);
    #pragma unroll
    for(int e=0;e<8;e++) vs[r][dg+e] = bf2f(v[e]);
  }
  float w[33];
  #pragma unroll
  for(int j=0;j<33;j++) w[j] = rw[h*33+j];
  __syncthreads();
  int d = t & 63, grp = t >> 6;
  float f0[16];
  #pragma unroll
  for(int rr=0;rr<16;rr++){
    int n = n0 + grp*16 + rr;
    f0[rr] = bf2f(F[(size_t)n*CDIM + h*DHEAD + d]);
  }
  float in[48];
  #pragma unroll
  for(int x=0;x<48;x++) in[x] = vs[grp*16 + x][d];
  #pragma unroll
  for(int rr=0;rr<16;rr++){
    float acc = 0.f;
    #pragma unroll
    for(int j=0;j<33;j++) acc += w[j]*in[rr+j];
    int n = n0 + grp*16 + rr;
    F[(size_t)n*CDIM + h*DHEAD + d] = (short)bfbits(f0[rr] + acc);
  }
}

// ---------------- weight transpose f32 -> bf16 ----------------
__global__ void k_transposeb(const float* __restrict__ in, short* __restrict__ out,
                             int R, int C){
  __shared__ float tile[32][33];
  int r0 = blockIdx.x*32, c0 = blockIdx.y*32;
  int tx = threadIdx.x, ty = threadIdx.y;
  #pragma unroll
  for(int r=0;r<4;r++) tile[ty + r*8][tx] = in[(size_t)(r0 + ty + r*8)*C + c0 + tx];
  __syncthreads();
  #pragma unroll
  for(int r=0;r<4;r++)
    out[(size_t)(c0 + ty + r*8)*R + r0 + tx] = (short)bfbits(tile[tx][ty + r*8]);
}

// ---------------- PPEG direct on row-major [n][c] (f32) ----------------
__global__ __launch_bounds__(256) void k_ppeg2(const float* __restrict__ X,
    const float* __restrict__ w7, const float* __restrict__ b7,
    const float* __restrict__ w5, const float* __restrict__ b5,
    const float* __restrict__ w3, const float* __restrict__ b3,
    float* __restrict__ Y){
  __shared__ float patch[484][20];
  int cg = blockIdx.y;
  int ti = blockIdx.x >> 3, tj = blockIdx.x & 7;
  int t = threadIdx.x;
  int i0 = ti*16 - 3, j0 = tj*16 - 3;
  for(int idx = t; idx < 1936; idx += 256){
    int p = idx >> 2, cq = (idx & 3) * 4;
    int gi = i0 + p/22, gj = j0 + p%22;
    float4 v = make_float4(0.f,0.f,0.f,0.f);
    if(gi>=0 && gi<128 && gj>=0 && gj<128)
      v = *(const float4*)(X + (size_t)(gi*128+gj)*CDIM + cg*16 + cq);
    *(float4*)&patch[p][cq] = v;
  }
  int c = t & 15, sg = t >> 4;
  int cglob = cg*16 + c;
  float wr[83];
  #pragma unroll
  for(int k=0;k<49;k++) wr[k] = w7[cglob*49+k];
  #pragma unroll
  for(int k=0;k<25;k++) wr[49+k] = w5[cglob*25+k];
  #pragma unroll
  for(int k=0;k<9;k++)  wr[74+k] = w3[cglob*9+k];
  float bsum = b7[cglob] + b5[cglob] + b3[cglob];
  __syncthreads();
  float acc[16];
  #pragma unroll
  for(int j=0;j<16;j++) acc[j] = patch[(sg+3)*22 + (j+3)][c] + bsum;
  #pragma unroll
  for(int a=0;a<7;a++)
    #pragma unroll
    for(int x=0;x<22;x++){
      float vv = patch[(sg+a)*22 + x][c];
      #pragma unroll
      for(int bq=0;bq<7;bq++){
        int j = x - bq;
        if(j>=0 && j<16) acc[j] += wr[a*7+bq]*vv;
      }
    }
  #pragma unroll
  for(int a=0;a<5;a++)
    #pragma unroll
    for(int x=1;x<21;x++){
      float vv = patch[(sg+a+1)*22 + x][c];
      #pragma unroll
      for(int bq=0;bq<5;bq++){
        int j = x - 1 - bq;
        if(j>=0 && j<16) acc[j] += wr[49+a*5+bq]*vv;
      }
    }
  #pragma unroll
  for(int a=0;a<3;a++)
    #pragma unroll
    for(int x=2;x<20;x++){
      float vv = patch[(sg+a+2)*22 + x][c];
      #pragma unroll
      for(int bq=0;bq<3;bq++){
        int j = x - 2 - bq;
        if(j>=0 && j<16) acc[j] += wr[74+a*3+bq]*vv;
      }
    }
  #pragma unroll
  for(int j=0;j<16;j++)
    Y[(size_t)((ti*16+sg)*128 + tj*16+j)*CDIM + cglob] = acc[j];
}

// ---------------- final LN(row0) + fc2 ----------------
__global__ __launch_bounds__(512) void k_final(const float* __restrict__ A,
    const float* __restrict__ g, const float* __restrict__ b,
    const float* __restrict__ w, const float* __restrict__ bias,
    float* __restrict__ outp){
  __shared__ float red[8];
  int t = threadIdx.x, wv = t >> 6;
  float x = A[t];
  float s = wave_sum(x);
  if((t & 63) == 0) red[wv] = s;
  __syncthreads();
  float mu = 0;
  #pragma unroll
  for(int i=0;i<8;i++) mu += red[i];
  mu *= (1.f/512.f);
  __syncthreads();
  float dx = x - mu;
  s = wave_sum(dx*dx);
  if((t & 63) == 0) red[wv] = s;
  __syncthreads();
  float var = 0;
  #pragma unroll
  for(int i=0;i<8;i++) var += red[i];
  var *= (1.f/512.f);
  float xn = dx * rsqrtf(var + 1e-5f) * g[t] + b[t];
  __syncthreads();
  for(int o=0;o<4;o++){
    s = wave_sum(xn * w[t*4 + o]);
    if((t & 63) == 0) red[wv] = s;
    __syncthreads();
    if(t == 0){
      float r = 0;
      #pragma unroll
      for(int i=0;i<8;i++) r += red[i];
      outp[o] = r + bias[o];
    }
    __syncthreads();
  }
}

extern "C" void kernel_launch(void* const* d_in, const int* in_sizes, int n_in,
                              void* d_out, int out_size, void* d_ws, size_t ws_size,
                              hipStream_t stream) {
  (void)in_sizes; (void)n_in; (void)out_size; (void)ws_size;
  const float* data_x = (const float*)d_in[0];
  const float* fc1_w  = (const float*)d_in[1];
  const float* fc1_b  = (const float*)d_in[2];
  const float* cls_tk = (const float*)d_in[3];
  const float* ng[2]  = {(const float*)d_in[4],  (const float*)d_in[16]};
  const float* nb[2]  = {(const float*)d_in[5],  (const float*)d_in[17]};
  const float* qkvw[2]= {(const float*)d_in[6],  (const float*)d_in[18]};
  const float* outw[2]= {(const float*)d_in[7],  (const float*)d_in[19]};
  const float* outb[2]= {(const float*)d_in[8],  (const float*)d_in[20]};
  const float* resw[2]= {(const float*)d_in[9],  (const float*)d_in[21]};
  const float* w7 = (const float*)d_in[10]; const float* pb7 = (const float*)d_in[11];
  const float* w5 = (const float*)d_in[12]; const float* pb5 = (const float*)d_in[13];
  const float* w3 = (const float*)d_in[14]; const float* pb3 = (const float*)d_in[15];
  const float* norm_g = (const float*)d_in[22];
  const float* norm_b = (const float*)d_in[23];
  const float* fc2_w  = (const float*)d_in[24];
  const float* fc2_b  = (const float*)d_in[25];

  float* ws = (float*)d_ws;
  float* Ab   = ws;
  float* Bb   = Ab + (size_t)TOK*CDIM;
  float* Fb   = Bb + (size_t)TOK*CDIM;
  short* Fbf  = (short*)(Fb + (size_t)NPAD*CDIM);
  short* lnX  = Fbf + (size_t)NPAD*CDIM;
  short* Qb   = lnX + (size_t)NPAD*CDIM;
  short* Kb   = Qb  + (size_t)NPAD*CDIM;
  short* Vb   = Kb  + (size_t)NPAD*CDIM;
  short* dxb  = Vb  + (size_t)NPAD*CDIM;
  float* qlb  = (float*)(dxb + (size_t)16384*1024);
  float* klb  = qlb + NHEAD*NLAND*DHEAD;
  float* a2b  = klb + NHEAD*NLAND*DHEAD;
  float* z0b  = a2b + NHEAD*NLAND*NLAND;
  float* z1b  = z0b + NHEAD*NLAND*NLAND;
  float* Xb_  = z1b + NHEAD*NLAND*NLAND;
  float* Tb_  = Xb_ + NHEAD*NLAND*NLAND;
  float* Ub_  = Tb_ + NHEAD*NLAND*NLAND;
  float* a3vb = Ub_ + NHEAD*NLAND*NLAND;
  float* w2tb = a3vb + NHEAD*NLAND*DHEAD;
  float* denP = w2tb + NHEAD*DHEAD*NLAND;
  float* hmax = denP + NHEAD*NCG*NLAND;
  float* scal = hmax + 8;
  short* fc1T = (short*)(scal + 8);
  short* qkvT0= fc1T + 512*1024;
  short* qkvT1= qkvT0 + 1536*512;
  short* outT0= qkvT1 + 1536*512;
  short* outT1= outT0 + 512*512;
  short* qkvT[2] = {qkvT0, qkvT1};
  short* outT[2] = {outT0, outT1};

  const int HB = NHEAD*NLAND*NLAND;
  short* zb0  = (short*)z0b;  short* zb1  = zb0 + HB;
  short* xb   = (short*)z1b;  short* tb   = xb + HB;
  short* ub   = (short*)Xb_;  short* a2bf = ub + HB;
  float* zf   = Tb_;

  k_transposeb<<<dim3(32,16), dim3(32,8), 0, stream>>>(fc1_w, fc1T, 1024, 512);
  k_transposeb<<<dim3(16,48), dim3(32,8), 0, stream>>>(qkvw[0], qkvT0, 512, 1536);
  k_transposeb<<<dim3(16,48), dim3(32,8), 0, stream>>>(qkvw[1], qkvT1, 512, 1536);
  k_transposeb<<<dim3(16,16), dim3(32,8), 0, stream>>>(outw[0], outT0, 512, 512);
  k_transposeb<<<dim3(16,16), dim3(32,8), 0, stream>>>(outw[1], outT1, 512, 512);
  k_f2b<<<8192, 256, 0, stream>>>(data_x, dxb, 16384*1024/8);

  k_copyrow<<<1, 512, 0, stream>>>(Ab, cls_tk);
  k_gemm_g<0><<<dim3(4, 128), 256, 0, stream>>>(dxb, 1024, fc1T, 1024, fc1_b,
                                                Ab + CDIM, nullptr, nullptr, 16384);
  float* base[2]  = {Ab, Bb};
  for(int L=0; L<2; L++){
    k_ln_pad<<<NPAD/4, 256, 0, stream>>>(base[L], ng[L], nb[L], lnX);
    k_gemm_g<1><<<dim3(12, 130), 256, 0, stream>>>(lnX, CDIM, qkvT[L], CDIM, nullptr,
                                                   Qb, Kb, Vb, NPAD);
    k_landmark2<<<2*NHEAD*NLAND, 64, 0, stream>>>(Qb, Kb, qlb, klb);
    k_a2_mfma<<<dim3(4, NHEAD), 256, 0, stream>>>(qlb, klb, a2b, a2bf);
    k_colmax<<<NHEAD, 256, 0, stream>>>(a2b, hmax);
    k_zinit<<<dim3(256, NHEAD), 256, 0, stream>>>(a2b, hmax, zb0);
    short* zc = zb0; short* zn = zb1;
    for(int it=0; it<6; it++){
      k_pgemm<0,0><<<dim3(4,4,NHEAD), 256, 0, stream>>>(a2bf, zc, xb, nullptr, 0.f, 1.f);
      k_pgemm<1,0><<<dim3(4,4,NHEAD), 256, 0, stream>>>(xb, xb, tb, nullptr, 7.f, 1.f);
      k_pgemm<1,0><<<dim3(4,4,NHEAD), 256, 0, stream>>>(xb, tb, ub, nullptr, 15.f, 1.f);
      if(it < 5){
        k_pgemm<1,0><<<dim3(4,4,NHEAD), 256, 0, stream>>>(zc, ub, zn, nullptr, 13.f, 0.25f);
        short* tmp = zc; zc = zn; zn = tmp;
      } else {
        k_pgemm<1,1><<<dim3(4,4,NHEAD), 256, 0, stream>>>(zc, ub, nullptr, zf, 13.f, 0.25f);
      }
    }
    k_a3v_mfma<<<dim3(NHEAD, NCG), 512, 0, stream>>>(qlb, Kb, Vb, Fb, denP);
    k_a3v_comb<<<NHEAD*NLAND, 64, 0, stream>>>(Fb, denP, a3vb);
    k_sgemm2<0,1><<<dim3(1,4,NHEAD), 256, 0, stream>>>(zf, a3vb, w2tb, 256,64,256,
                                                       65536,16384,16384, 0.f, 1.f);
    k_a1_mfma<<<dim3(130, NHEAD), 256, 0, stream>>>(Qb, klb, w2tb, Fbf);
    k_resconv<<<dim3(260, NHEAD), 256, 0, stream>>>(Vb, resw[L], Fbf);
    k_gemm_g<2><<<dim3(4, 129), 256, 0, stream>>>(Fbf + (size_t)PAD0*CDIM, CDIM,
                                                  outT[L], CDIM, outb[L],
                                                  base[L], nullptr, nullptr, TOK);
    if(L == 0){
      k_ppeg2<<<dim3(64, 32), 256, 0, stream>>>(Ab + CDIM, w7, pb7, w5, pb5, w3, pb3,
                                                Bb + CDIM);
      k_copyrow<<<1, 512, 0, stream>>>(Bb, Ab);
    }
  }
  k_final<<<1, 512, 0, stream>>>(Bb, norm_g, norm_b, fc2_w, fc2_b, (float*)d_out);
}

// Round 21
// 915.251 us; speedup vs baseline: 1.0179x; 1.0179x over previous
//
#include <hip/hip_runtime.h>
#include <hip/hip_bf16.h>

#define NPAD 16640
#define TOK  16385
#define CDIM 512
#define NHEAD 8
#define DHEAD 64
#define NLAND 256
#define LFAC  65
#define PAD0  255
#define NCHUNK 65     // 256-row chunks
#define CGRP 2        // chunks per block in a3v
#define NCG 33        // ceil(65/2)

typedef __attribute__((ext_vector_type(8))) short sh8;
typedef __attribute__((ext_vector_type(4))) float f4;

__device__ __forceinline__ float wave_sum(float v){
  #pragma unroll
  for(int o=32;o;o>>=1) v += __shfl_xor(v,o);
  return v;
}
__device__ __forceinline__ float wave_max(float v){
  #pragma unroll
  for(int o=32;o;o>>=1) v = fmaxf(v, __shfl_xor(v,o));
  return v;
}

__device__ __forceinline__ unsigned bfbits(float x){
  unsigned u = __float_as_uint(x);
  return (u + 0x7fffu + ((u >> 16) & 1u)) >> 16;
}
__device__ __forceinline__ float bf2f(short s){
  return __uint_as_float(((unsigned)(unsigned short)s) << 16);
}
__device__ __forceinline__ sh8 pack8f(float4 a, float4 b){
  sh8 r;
  r[0]=(short)bfbits(a.x); r[1]=(short)bfbits(a.y); r[2]=(short)bfbits(a.z); r[3]=(short)bfbits(a.w);
  r[4]=(short)bfbits(b.x); r[5]=(short)bfbits(b.y); r[6]=(short)bfbits(b.z); r[7]=(short)bfbits(b.w);
  return r;
}
#define MFMA16(a,b,c) __builtin_amdgcn_mfma_f32_16x16x32_bf16(a,b,c,0,0,0)

__device__ __forceinline__ void gload16(const void* g, void* l){
  __builtin_amdgcn_global_load_lds(
      (const __attribute__((address_space(1))) void*)g,
      (__attribute__((address_space(3))) void*)l, 16, 0, 0);
}

// lgkm-only barrier: drains LDS ops but leaves global prefetch (vmcnt) in flight
#define BAR_LGKM() do{ \
  asm volatile("s_waitcnt lgkmcnt(0)" ::: "memory"); \
  __builtin_amdgcn_s_barrier(); \
  __builtin_amdgcn_sched_barrier(0); \
}while(0)

// ---------------- row copy (cls token) ----------------
__global__ void k_copyrow(float* dst, const float* __restrict__ src){
  dst[threadIdx.x] = src[threadIdx.x];
}

// ---------------- f32 -> bf16 convert ----------------
__global__ __launch_bounds__(256) void k_f2b(const float* __restrict__ in,
    short* __restrict__ out, int n8){
  int i = blockIdx.x*256 + threadIdx.x;
  if(i < n8){
    float4 a = *(const float4*)(in + (size_t)i*8);
    float4 b = *(const float4*)(in + (size_t)i*8 + 4);
    *(sh8*)(out + (size_t)i*8) = pack8f(a, b);
  }
}

// ---------------- layernorm + front pad -> bf16 ----------------
__global__ __launch_bounds__(256) void k_ln_pad(const float* __restrict__ A,
    const float* __restrict__ g, const float* __restrict__ b, short* __restrict__ B){
  int w = threadIdx.x >> 6, lane = threadIdx.x & 63;
  int row = blockIdx.x*4 + w;
  short* out = B + (size_t)row*CDIM;
  int c = lane*8;
  if(row < PAD0){
    sh8 z = {0,0,0,0,0,0,0,0};
    *(sh8*)(out + c) = z;
    return;
  }
  const float* x = A + (size_t)(row-PAD0)*CDIM;
  float4 v0 = *(const float4*)(x + c);
  float4 v1 = *(const float4*)(x + c + 4);
  float xs[8] = {v0.x,v0.y,v0.z,v0.w,v1.x,v1.y,v1.z,v1.w};
  float s = 0;
  #pragma unroll
  for(int i=0;i<8;i++) s += xs[i];
  s = wave_sum(s);
  float mu = s * (1.f/512.f);
  float vs = 0;
  #pragma unroll
  for(int i=0;i<8;i++){ float d = xs[i]-mu; vs += d*d; }
  vs = wave_sum(vs) * (1.f/512.f);
  float rs = rsqrtf(vs + 1e-5f);
  float4 g0 = *(const float4*)(g + c); float4 g1 = *(const float4*)(g + c + 4);
  float4 b0 = *(const float4*)(b + c); float4 b1 = *(const float4*)(b + c + 4);
  float gg[8] = {g0.x,g0.y,g0.z,g0.w,g1.x,g1.y,g1.z,g1.w};
  float bb[8] = {b0.x,b0.y,b0.z,b0.w,b1.x,b1.y,b1.z,b1.w};
  sh8 o;
  #pragma unroll
  for(int i=0;i<8;i++) o[i] = (short)bfbits((xs[i]-mu)*rs*gg[i] + bb[i]);
  *(sh8*)(out + c) = o;
}

// ---------------- gload-staged MFMA GEMM, 256x128 tile, 512 threads -------------
// C[M,N] = A[M,K] @ WT[N,K]^T, A/WT bf16. BK=32, double-buffered, counted vmcnt.
// 8 waves: 4 m-groups x 2 n-groups of 64x64. Per thread 3 gload16 per K-step.
// MODE 0: fc1 relu(acc+bias)->f32 ; MODE 1: qkv scatter head-major bf16, q*0.125 ;
// MODE 2: proj f32 += acc+bias
template<int MODE>
__global__ __launch_bounds__(512) void k_gemm_g(const short* __restrict__ A, int lda,
    const short* __restrict__ WT, int K, const float* __restrict__ bias,
    void* out0v, void* out1v, void* out2v, int M){
  __shared__ short As[2][256*32];
  __shared__ short Bs[2][128*32];
  int t = threadIdx.x, lane = t & 63, wv = t >> 6, g = lane >> 4, l15 = lane & 15;
  int nwg = gridDim.x * gridDim.y;
  int orig = blockIdx.y * gridDim.x + blockIdx.x;
  int qc = nwg >> 3, rc = nwg & 7, xcd = orig & 7, loc = orig >> 3;
  int wgid = (xcd < rc ? xcd*(qc+1) : rc*(qc+1) + (xcd - rc)*qc) + loc;
  int row0 = (wgid / gridDim.x) * 256, n0 = (wgid % gridDim.x) * 128;
  int wm = (wv >> 1)*64, wn = (wv & 1)*64;
  int mq = lane >> 2, slot = lane & 3;

  // stage one (256+128)x32 K-tile into buffer buf: 3 gload16 per thread
  auto stage = [&](int buf, int k0){
    #pragma unroll
    for(int c=0;c<2;c++){
      int m = c*128 + wv*16 + mq;          // A rows
      int swz = (((m&3) ^ ((m>>2)&3)) << 4);
      int gr = row0 + m; if(gr >= M) gr = M-1;
      const char* srcA = (const char*)(A + (size_t)gr*lda + k0) + ((slot*16) ^ swz);
      gload16(srcA, (char*)As[buf] + (c*128 + wv*16)*64);
    }
    {
      int m = wv*16 + mq;                  // B rows (128)
      int swz = (((m&3) ^ ((m>>2)&3)) << 4);
      const char* srcB = (const char*)(WT + (size_t)(n0+m)*K + k0) + ((slot*16) ^ swz);
      gload16(srcB, (char*)Bs[buf] + (wv*16)*64);
    }
  };

  f4 acc[4][4] = {};
  int nk = K >> 5;
  stage(0, 0);                       // 3 vm ops/thread in flight
  int cur = 0;
  for(int i=0; i<nk; i++){
    if(i+1 < nk){
      stage(cur^1, (i+1) << 5);      // +3 vm ops (6 outstanding)
      asm volatile("s_waitcnt vmcnt(3)" ::: "memory");  // current tile landed
    } else {
      asm volatile("s_waitcnt vmcnt(0)" ::: "memory");
    }
    __builtin_amdgcn_s_barrier();
    __builtin_amdgcn_sched_barrier(0);
    sh8 af[4], bf[4];
    #pragma unroll
    for(int mt=0; mt<4; mt++){
      int r = wm + mt*16 + l15;
      af[mt] = *(sh8*)((char*)As[cur] + r*64 + ((g*16) ^ (((r&3)^((r>>2)&3))<<4)));
    }
    #pragma unroll
    for(int nt=0; nt<4; nt++){
      int r = wn + nt*16 + l15;
      bf[nt] = *(sh8*)((char*)Bs[cur] + r*64 + ((g*16) ^ (((r&3)^((r>>2)&3))<<4)));
    }
    #pragma unroll
    for(int mt=0; mt<4; mt++)
      #pragma unroll
      for(int nt=0; nt<4; nt++)
        acc[mt][nt] = MFMA16(af[mt], bf[nt], acc[mt][nt]);
    BAR_LGKM();                      // LDS reads done before reuse; vm stays live
    cur ^= 1;
  }
  #pragma unroll
  for(int mt=0; mt<4; mt++){
    #pragma unroll
    for(int r=0; r<4; r++){
      int gm = row0 + wm + mt*16 + g*4 + r;
      if(gm >= M) continue;
      #pragma unroll
      for(int nt=0; nt<4; nt++){
        int gn = n0 + wn + nt*16 + l15;
        float v = acc[mt][nt][r];
        if(MODE == 0){
          v += bias[gn];
          ((float*)out0v)[(size_t)gm*CDIM + gn] = v > 0.f ? v : 0.f;
        } else if(MODE == 1){
          int p = gn >> 9, rr = gn & 511;
          int hh = rr >> 6, dd = rr & 63;
          if(p == 0) v *= 0.125f;
          short* dst = (p==0) ? (short*)out0v : (p==1 ? (short*)out1v : (short*)out2v);
          dst[((size_t)hh*NPAD + gm)*DHEAD + dd] = (short)bfbits(v);
        } else {
          ((float*)out0v)[(size_t)gm*CDIM + gn] += v + bias[gn];
        }
      }
    }
  }
}

// ---------------- landmark means, Q and K in one dispatch ----------------
__global__ void k_landmark2(const short* __restrict__ Qb, const short* __restrict__ Kb,
    float* __restrict__ ql, float* __restrict__ kl){
  int bidx = blockIdx.x;
  int sel = bidx >> 11;
  int loc = bidx & 2047;
  int h = loc >> 8, m = loc & 255, d = threadIdx.x;
  const short* src = (sel ? Kb : Qb) + ((size_t)h*NPAD + (size_t)m*LFAC)*DHEAD + d;
  float s = 0;
  for(int j=0;j<LFAC;j++) s += bf2f(src[(size_t)j*DHEAD]);
  (sel ? kl : ql)[(size_t)loc*DHEAD + d] = s * (1.f/LFAC);
}

// ---------------- a2 = softmax(ql @ kl^T), MFMA ----------------
__global__ __launch_bounds__(256) void k_a2_mfma(const float* __restrict__ ql,
    const float* __restrict__ kl, float* __restrict__ a2, short* __restrict__ a2bf){
  __shared__ short klL[256*64];   // [n][d] bf16, 128B rows, XOR swizzle
  int q = blockIdx.x, h = blockIdx.y;
  int t = threadIdx.x, lane = t & 63, wv = t >> 6, g = lane >> 4, l15 = lane & 15;
  const float* qlh = ql + (size_t)h*NLAND*DHEAD;
  const float* klh = kl + (size_t)h*NLAND*DHEAD;
  #pragma unroll
  for(int i=0;i<8;i++){
    int gi = t + i*256;
    int n = gi >> 3, db = (gi & 7)*8;
    float4 a = *(const float4*)(klh + (size_t)n*DHEAD + db);
    float4 b = *(const float4*)(klh + (size_t)n*DHEAD + db + 4);
    *(sh8*)((char*)klL + n*128 + ((db*2) ^ ((n&7)<<4))) = pack8f(a, b);
  }
  __syncthreads();
  int row0 = q*64 + wv*16;
  sh8 aQ[2];
  #pragma unroll
  for(int kk=0; kk<2; kk++){
    const float* p = qlh + (size_t)(row0 + l15)*DHEAD + kk*32 + g*8;
    aQ[kk] = pack8f(*(const float4*)p, *(const float4*)(p+4));
  }
  f4 acc[16];
  #pragma unroll
  for(int nt=0; nt<16; nt++){
    f4 s = {};
    #pragma unroll
    for(int kk=0; kk<2; kk++){
      int n = nt*16 + l15;
      sh8 b = *(sh8*)((char*)klL + n*128 + ((kk*64 + g*16) ^ ((n&7)<<4)));
      s = MFMA16(aQ[kk], b, s);
    }
    acc[nt] = s;
  }
  float den[4] = {0,0,0,0};
  #pragma unroll
  for(int nt=0; nt<16; nt++)
    #pragma unroll
    for(int r=0; r<4; r++){
      float e = __expf(acc[nt][r]);
      acc[nt][r] = e;
      den[r] += e;
    }
  #pragma unroll
  for(int r=0; r<4; r++){
    float d_ = den[r];
    d_ += __shfl_xor(d_,1); d_ += __shfl_xor(d_,2);
    d_ += __shfl_xor(d_,4); d_ += __shfl_xor(d_,8);
    den[r] = 1.f/d_;
  }
  #pragma unroll
  for(int nt=0; nt<16; nt++)
    #pragma unroll
    for(int r=0; r<4; r++){
      int row = row0 + g*4 + r;
      int col = nt*16 + l15;
      float v = acc[nt][r]*den[r];
      size_t idx = ((size_t)h*NLAND + row)*NLAND + col;
      a2[idx] = v;
      a2bf[idx] = (short)bfbits(v);
    }
}

// ---------------- pinv init ----------------
__global__ void k_colmax(const float* __restrict__ a2, float* __restrict__ hmax){
  __shared__ float red[4];
  int h = blockIdx.x, t = threadIdx.x;
  const float* p = a2 + (size_t)h*65536 + t;
  float s = 0;
  for(int m=0;m<256;m++) s += p[(size_t)m*256];
  float mx = wave_max(s);
  if((t & 63) == 0) red[t>>6] = mx;
  __syncthreads();
  if(t == 0) hmax[h] = fmaxf(fmaxf(red[0],red[1]), fmaxf(red[2],red[3]));
}
// z0 (bf16) = a2^T / max(hmax)
__global__ void k_zinit(const float* __restrict__ a2, const float* __restrict__ hmax,
                        short* __restrict__ z){
  int h = blockIdx.y;
  int idx = blockIdx.x*256 + threadIdx.x;
  int m = idx >> 8, j = idx & 255;
  float mx = hmax[0];
  #pragma unroll
  for(int i=1;i<8;i++) mx = fmaxf(mx, hmax[i]);
  z[(size_t)h*65536 + idx] = (short)bfbits(a2[(size_t)h*65536 + (size_t)j*256 + m] / mx);
}

// ---------------- batched MFMA pinv GEMM, bf16 I/O ----------------
template<int TRANS, int F32OUT>
__global__ __launch_bounds__(256) void k_pgemm(const short* __restrict__ A,
    const short* __restrict__ B, short* __restrict__ C, float* __restrict__ Cf,
    float alpha, float beta){
  __shared__ short As[64*32];
  __shared__ short Bs[64*32];
  int bh = blockIdx.z;
  const short* Ah = A + (size_t)bh*65536;
  const short* Bh = B + (size_t)bh*65536;
  int m0 = blockIdx.y*64, n0 = blockIdx.x*64;
  int t = threadIdx.x, lane = t & 63, wv = t >> 6, g = lane >> 4, l15 = lane & 15;
  f4 acc[4] = {};
  for(int k0=0; k0<256; k0+=32){
    {
      int m = t >> 2, kb = (t & 3)*8;
      sh8 av = *(const sh8*)(Ah + (size_t)(m0+m)*256 + k0 + kb);
      int swz = (((m&3)^((m>>2)&3))<<4);
      *(sh8*)((char*)As + m*64 + ((kb*2)^swz)) = av;
    }
    {
      int kr = t >> 3, nb = (t & 7)*8;
      sh8 bv = *(const sh8*)(Bh + (size_t)(k0+kr)*256 + n0 + nb);
      #pragma unroll
      for(int e=0;e<8;e++){
        int n = nb + e;
        short sv = bv[e];
        if(TRANS){
          float f = ((k0+kr == n0+n) ? alpha : 0.f) - bf2f(sv);
          sv = (short)bfbits(f);
        }
        int swz = (((n&3)^((n>>2)&3))<<4);
        *(short*)((char*)Bs + n*64 + ((kr*2)^swz)) = sv;
      }
    }
    __syncthreads();
    int rm = wv*16 + l15;
    sh8 af = *(sh8*)((char*)As + rm*64 + ((g*16) ^ (((rm&3)^((rm>>2)&3))<<4)));
    #pragma unroll
    for(int nt=0; nt<4; nt++){
      int n = nt*16 + l15;
      sh8 bf = *(sh8*)((char*)Bs + n*64 + ((g*16) ^ (((n&3)^((n>>2)&3))<<4)));
      acc[nt] = MFMA16(af, bf, acc[nt]);
    }
    __syncthreads();
  }
  size_t hoff = (size_t)bh*65536;
  #pragma unroll
  for(int nt=0; nt<4; nt++)
    #pragma unroll
    for(int r=0; r<4; r++){
      size_t idx = hoff + (size_t)(m0 + wv*16 + g*4 + r)*256 + n0 + nt*16 + l15;
      float v = acc[nt][r]*beta;
      if(F32OUT) Cf[idx] = v;
      else       C[idx] = (short)bfbits(v);
    }
}

// ---------------- batched f32 GEMM 64x64 tile (w2^T only) ----------------
template<int TRANS, int OUTT>
__global__ __launch_bounds__(256) void k_sgemm2(const float* __restrict__ A,
    const float* __restrict__ B, float* __restrict__ C,
    int M, int N, int K, long sA, long sB, long sC, float alpha, float beta){
  __shared__ float As[32][68];
  __shared__ float Bs[32][68];
  int bh = blockIdx.z;
  const float* Ah = A + (size_t)bh*sA;
  const float* Bh = B + (size_t)bh*sB;
  float* Ch = C + (size_t)bh*sC;
  int m0 = blockIdx.y*64, n0 = blockIdx.x*64;
  int t = threadIdx.x, tx = t & 15, ty = t >> 4;
  float acc[4][4] = {};
  for(int k0=0; k0<K; k0+=32){
    #pragma unroll
    for(int u=0; u<2; u++){
      int idx = t + u*256;
      int r = idx >> 3, cb = (idx & 7) * 4;
      float4 va = *(const float4*)(Ah + (size_t)(m0+r)*K + k0 + cb);
      As[cb+0][r]=va.x; As[cb+1][r]=va.y; As[cb+2][r]=va.z; As[cb+3][r]=va.w;
      int kr = idx >> 4, nb = (idx & 15) * 4;
      float4 w = *(const float4*)(Bh + (size_t)(k0+kr)*N + n0 + nb);
      if(TRANS){
        int gk = k0 + kr;
        w.x = ((gk==n0+nb+0)?alpha:0.f) - w.x;
        w.y = ((gk==n0+nb+1)?alpha:0.f) - w.y;
        w.z = ((gk==n0+nb+2)?alpha:0.f) - w.z;
        w.w = ((gk==n0+nb+3)?alpha:0.f) - w.w;
      }
      *(float4*)&Bs[kr][nb] = w;
    }
    __syncthreads();
    #pragma unroll
    for(int k=0;k<32;k++){
      float a[4], b[4];
      *(float4*)a = *(const float4*)&As[k][ty*4];
      *(float4*)b = *(const float4*)&Bs[k][tx*4];
      #pragma unroll
      for(int i=0;i<4;i++)
        #pragma unroll
        for(int j=0;j<4;j++) acc[i][j] += a[i]*b[j];
    }
    __syncthreads();
  }
  #pragma unroll
  for(int i=0;i<4;i++){
    #pragma unroll
    for(int j=0;j<4;j++){
      int gm = m0 + ty*4 + i, gn = n0 + tx*4 + j;
      float v = acc[i][j] * beta;
      if(OUTT) Ch[(size_t)gn*M + gm] = v;
      else     Ch[(size_t)gm*N + gn] = v;
    }
  }
}

// ---------------- MFMA flash a1 (Q bf16, F out bf16), per-wave P ----------------
__global__ __launch_bounds__(256) void k_a1_mfma(const short* __restrict__ Qb,
    const float* __restrict__ kl, const float* __restrict__ w2t, short* __restrict__ F){
  __shared__ short klL[128*64];
  __shared__ short w2L[64*128];
  __shared__ short pL[4][16*128];
  int h = blockIdx.y, n0 = blockIdx.x*128;
  int t = threadIdx.x, lane = t & 63, wv = t >> 6, g = lane >> 4, l15 = lane & 15;
  const float* klh = kl + (size_t)h*NLAND*DHEAD;
  const float* w2h = w2t + (size_t)h*DHEAD*NLAND;
  const short* qbase = Qb + (size_t)h*NPAD*DHEAD;
  sh8 aQ[2][2];
  #pragma unroll
  for(int st=0; st<2; st++)
    #pragma unroll
    for(int kk=0; kk<2; kk++)
      aQ[st][kk] = *(const sh8*)(qbase +
          (size_t)(n0 + wv*32 + st*16 + l15)*DHEAD + kk*32 + g*8);
  f4 accO[2][4] = {};
  float den[2][4] = {};
  short* pw = pL[wv];
  for(int half=0; half<2; half++){
    __syncthreads();
    #pragma unroll
    for(int it=0; it<4; it++){
      int gi = t + it*256;
      int m = gi >> 3, db = (gi & 7) * 8;
      const float* p = klh + (size_t)(half*128 + m)*DHEAD + db;
      *(sh8*)((char*)klL + m*128 + ((db*2) ^ ((m&7)<<4))) =
          pack8f(*(const float4*)p, *(const float4*)(p+4));
      int d = gi >> 4, mb = (gi & 15) * 8;
      const float* p2 = w2h + (size_t)d*NLAND + half*128 + mb;
      *(sh8*)((char*)w2L + d*256 + ((mb*2) ^ ((d&7)<<4))) =
          pack8f(*(const float4*)p2, *(const float4*)(p2+4));
    }
    __syncthreads();
    #pragma unroll
    for(int st=0; st<2; st++){
      #pragma unroll
      for(int mt=0; mt<8; mt++){
        f4 s = {};
        #pragma unroll
        for(int kk=0; kk<2; kk++){
          int m = mt*16 + l15;
          sh8 b = *(sh8*)((char*)klL + m*128 + ((kk*64 + g*16) ^ ((m&7)<<4)));
          s = MFMA16(aQ[st][kk], b, s);
        }
        #pragma unroll
        for(int r=0; r<4; r++){
          float e = __expf(s[r]);
          den[st][r] += e;
          int n = g*4 + r;
          *(short*)((char*)pw + n*256 + (((mt*16+l15)*2) ^ ((n&7)<<4))) = (short)bfbits(e);
        }
      }
      #pragma unroll
      for(int ks=0; ks<4; ks++){
        sh8 aP = *(sh8*)((char*)pw + l15*256 + ((ks*64 + g*16) ^ ((l15&7)<<4)));
        #pragma unroll
        for(int dt=0; dt<4; dt++){
          int d = dt*16 + l15;
          sh8 bW = *(sh8*)((char*)w2L + d*256 + ((ks*64 + g*16) ^ ((d&7)<<4)));
          accO[st][dt] = MFMA16(aP, bW, accO[st][dt]);
        }
      }
    }
  }
  #pragma unroll
  for(int st=0; st<2; st++)
    #pragma unroll
    for(int r=0; r<4; r++){
      float d_ = den[st][r];
      d_ += __shfl_xor(d_,1); d_ += __shfl_xor(d_,2);
      d_ += __shfl_xor(d_,4); d_ += __shfl_xor(d_,8);
      den[st][r] = 1.f/d_;
    }
  #pragma unroll
  for(int st=0; st<2; st++)
    #pragma unroll
    for(int dt=0; dt<4; dt++)
      #pragma unroll
      for(int r=0; r<4; r++){
        int row = n0 + wv*32 + st*16 + g*4 + r;
        F[(size_t)row*CDIM + h*DHEAD + dt*16 + l15] =
            (short)bfbits(accO[st][dt][r]*den[st][r]);
      }
}

// ---------------- MFMA flash a3v: 8 waves, lgkm-only barriers, reg prefetch ------
__global__ __launch_bounds__(512) void k_a3v_mfma(const float* __restrict__ ql,
    const short* __restrict__ Kb, const short* __restrict__ Vb,
    float* __restrict__ numP, float* __restrict__ denP){
  __shared__ short kL[128*64];
  __shared__ short vL[64*128];
  __shared__ short pL[8][16*128];
  int h = blockIdx.x, cg = blockIdx.y;
  int t = threadIdx.x, lane = t & 63, wv = t >> 6, g = lane >> 4, l15 = lane & 15;
  int r0 = (wv & 3)*64 + (wv >> 2)*32;
  const float* qlh = ql + (size_t)h*NLAND*DHEAD;
  sh8 aQ[2][2];
  #pragma unroll
  for(int st=0; st<2; st++)
    #pragma unroll
    for(int kk=0; kk<2; kk++){
      const float* p = qlh + (size_t)(r0 + st*16 + l15)*DHEAD + kk*32 + g*8;
      aQ[st][kk] = pack8f(*(const float4*)p, *(const float4*)(p+4));
    }
  f4 accO[2][4] = {};
  float den[2][4] = {};
  short* pw = pL[wv];

  int km[2], kdb[2];
  #pragma unroll
  for(int it=0; it<2; it++){
    int gi = t + it*512;
    km[it] = gi >> 3; kdb[it] = (gi & 7) * 8;
  }
  int vmp = (t & 63)*2, vdg = (t >> 6)*8;

  sh8 kreg[2], vreg[2];
  auto ldregs = [&](int ph){
    int c = cg*CGRP + (ph >> 1), half = ph & 1;
    const short* Kh = Kb + ((size_t)h*NPAD + (size_t)c*256 + half*128)*DHEAD;
    const short* Vh = Vb + ((size_t)h*NPAD + (size_t)c*256 + half*128)*DHEAD;
    #pragma unroll
    for(int it=0; it<2; it++)
      kreg[it] = *(const sh8*)(Kh + (size_t)km[it]*DHEAD + kdb[it]);
    vreg[0] = *(const sh8*)(Vh + (size_t)vmp*DHEAD + vdg);
    vreg[1] = *(const sh8*)(Vh + (size_t)(vmp+1)*DHEAD + vdg);
  };

  int nph = 2*CGRP;
  if(cg*CGRP + ((nph-1) >> 1) >= NCHUNK) nph = 2;
  ldregs(0);
  for(int ph=0; ph<nph; ph++){
    BAR_LGKM();
    #pragma unroll
    for(int it=0; it<2; it++)
      *(sh8*)((char*)kL + km[it]*128 + ((kdb[it]*2) ^ ((km[it]&7)<<4))) = kreg[it];
    {
      sh8 v0 = vreg[0], v1 = vreg[1];
      #pragma unroll
      for(int i=0;i<8;i++){
        int d = vdg + i;
        unsigned pk = ((unsigned)(unsigned short)v0[i]) |
                      (((unsigned)(unsigned short)v1[i]) << 16);
        *(unsigned*)((char*)vL + d*256 + ((vmp*2) ^ ((d&7)<<4))) = pk;
      }
    }
    if(ph+1 < nph) ldregs(ph+1);
    BAR_LGKM();
    #pragma unroll
    for(int st=0; st<2; st++){
      #pragma unroll
      for(int mt=0; mt<8; mt++){
        f4 s = {};
        #pragma unroll
        for(int kk=0; kk<2; kk++){
          int m = mt*16 + l15;
          sh8 b = *(sh8*)((char*)kL + m*128 + ((kk*64 + g*16) ^ ((m&7)<<4)));
          s = MFMA16(aQ[st][kk], b, s);
        }
        #pragma unroll
        for(int r=0; r<4; r++){
          float e = __expf(s[r]);
          den[st][r] += e;
          int n = g*4 + r;
          *(short*)((char*)pw + n*256 + (((mt*16+l15)*2) ^ ((n&7)<<4))) = (short)bfbits(e);
        }
      }
      #pragma unroll
      for(int ks=0; ks<4; ks++){
        sh8 aP = *(sh8*)((char*)pw + l15*256 + ((ks*64 + g*16) ^ ((l15&7)<<4)));
        #pragma unroll
        for(int dt=0; dt<4; dt++){
          int d = dt*16 + l15;
          sh8 bV = *(sh8*)((char*)vL + d*256 + ((ks*64 + g*16) ^ ((d&7)<<4)));
          accO[st][dt] = MFMA16(aP, bV, accO[st][dt]);
        }
      }
    }
  }
  #pragma unroll
  for(int st=0; st<2; st++)
    #pragma unroll
    for(int r=0; r<4; r++){
      float d_ = den[st][r];
      d_ += __shfl_xor(d_,1); d_ += __shfl_xor(d_,2);
      d_ += __shfl_xor(d_,4); d_ += __shfl_xor(d_,8);
      den[st][r] = d_;
    }
  size_t base = ((size_t)h*NCG + cg)*NLAND;
  #pragma unroll
  for(int st=0; st<2; st++){
    #pragma unroll
    for(int r=0; r<4; r++){
      int row = r0 + st*16 + g*4 + r;
      if(l15 == 0) denP[base + row] = den[st][r];
      #pragma unroll
      for(int dt=0; dt<4; dt++)
        numP[(base + row)*DHEAD + dt*16 + l15] = accO[st][dt][r];
    }
  }
}

__global__ void k_a3v_comb(const float* __restrict__ numP, const float* __restrict__ denP,
                           float* __restrict__ a3v){
  int bidx = blockIdx.x;
  int h = bidx >> 8, m = bidx & 255;
  int d = threadIdx.x;
  float s = 0.f, den = 0.f;
  for(int c=0;c<NCG;c++){
    s += numP[(((size_t)h*NCG + c)*NLAND + m)*DHEAD + d];
    den += denP[((size_t)h*NCG + c)*NLAND + m];
  }
  a3v[((size_t)h*NLAND + m)*DHEAD + d] = s / den;
}

// ---------------- residual depthwise conv (k=33), register-FIR ----------------
__global__ __launch_bounds__(256) void k_resconv(const short* __restrict__ Vb,
    const float* __restrict__ rw, short* __restrict__ F){
  __shared__ float vs[96][64];
  int n0 = blockIdx.x*64, h = blockIdx.y;
  int t = threadIdx.x;
  const short* vh = Vb + (size_t)h*NPAD*DHEAD;
  #pragma unroll
  for(int i=0;i<3;i++){
    int idx = t + i*256;
    int r = idx >> 3, dg = (idx & 7)*8;
    int n = n0 - 16 + r;
    sh8 v = {0,0,0,0,0,0,0,0};
    if(n>=0 && n<NPAD) v = *(const sh8*)(vh + (size_t)n*DHEAD + dg);
    #pragma unroll
    for(int e=0;e<8;e++) vs[r][dg+e] = bf2f(v[e]);
  }
  float w[33];
  #pragma unroll
  for(int j=0;j<33;j++) w[j] = rw[h*33+j];
  __syncthreads();
  int d = t & 63, grp = t >> 6;
  float f0[16];
  #pragma unroll
  for(int rr=0;rr<16;rr++){
    int n = n0 + grp*16 + rr;
    f0[rr] = bf2f(F[(size_t)n*CDIM + h*DHEAD + d]);
  }
  float in[48];
  #pragma unroll
  for(int x=0;x<48;x++) in[x] = vs[grp*16 + x][d];
  #pragma unroll
  for(int rr=0;rr<16;rr++){
    float acc = 0.f;
    #pragma unroll
    for(int j=0;j<33;j++) acc += w[j]*in[rr+j];
    int n = n0 + grp*16 + rr;
    F[(size_t)n*CDIM + h*DHEAD + d] = (short)bfbits(f0[rr] + acc);
  }
}

// ---------------- batched weight transpose f32 -> bf16 (5 jobs, grid.z) ---------
__global__ void k_transb5(
    const float* s0, short* d0, int R0, int C0,
    const float* s1, short* d1, int R1, int C1,
    const float* s2, short* d2, int R2, int C2,
    const float* s3, short* d3, int R3, int C3,
    const float* s4, short* d4, int R4, int C4){
  const float* in; short* out; int R, C;
  switch(blockIdx.z){
    case 0: in=s0; out=d0; R=R0; C=C0; break;
    case 1: in=s1; out=d1; R=R1; C=C1; break;
    case 2: in=s2; out=d2; R=R2; C=C2; break;
    case 3: in=s3; out=d3; R=R3; C=C3; break;
    default: in=s4; out=d4; R=R4; C=C4; break;
  }
  __shared__ float tile[32][33];
  int r0 = blockIdx.x*32, c0 = blockIdx.y*32;
  if(r0 >= R || c0 >= C) return;
  int tx = threadIdx.x, ty = threadIdx.y;
  #pragma unroll
  for(int r=0;r<4;r++) tile[ty + r*8][tx] = in[(size_t)(r0 + ty + r*8)*C + c0 + tx];
  __syncthreads();
  #pragma unroll
  for(int r=0;r<4;r++)
    out[(size_t)(c0 + ty + r*8)*R + r0 + tx] = (short)bfbits(tile[tx][ty + r*8]);
}

// ---------------- PPEG direct on row-major [n][c] (f32) ----------------
__global__ __launch_bounds__(256) void k_ppeg2(const float* __restrict__ X,
    const float* __restrict__ w7, const float* __restrict__ b7,
    const float* __restrict__ w5, const float* __restrict__ b5,
    const float* __restrict__ w3, const float* __restrict__ b3,
    float* __restrict__ Y){
  __shared__ float patch[484][20];
  int cg = blockIdx.y;
  int ti = blockIdx.x >> 3, tj = blockIdx.x & 7;
  int t = threadIdx.x;
  int i0 = ti*16 - 3, j0 = tj*16 - 3;
  for(int idx = t; idx < 1936; idx += 256){
    int p = idx >> 2, cq = (idx & 3) * 4;
    int gi = i0 + p/22, gj = j0 + p%22;
    float4 v = make_float4(0.f,0.f,0.f,0.f);
    if(gi>=0 && gi<128 && gj>=0 && gj<128)
      v = *(const float4*)(X + (size_t)(gi*128+gj)*CDIM + cg*16 + cq);
    *(float4*)&patch[p][cq] = v;
  }
  int c = t & 15, sg = t >> 4;
  int cglob = cg*16 + c;
  float wr[83];
  #pragma unroll
  for(int k=0;k<49;k++) wr[k] = w7[cglob*49+k];
  #pragma unroll
  for(int k=0;k<25;k++) wr[49+k] = w5[cglob*25+k];
  #pragma unroll
  for(int k=0;k<9;k++)  wr[74+k] = w3[cglob*9+k];
  float bsum = b7[cglob] + b5[cglob] + b3[cglob];
  __syncthreads();
  float acc[16];
  #pragma unroll
  for(int j=0;j<16;j++) acc[j] = patch[(sg+3)*22 + (j+3)][c] + bsum;
  #pragma unroll
  for(int a=0;a<7;a++)
    #pragma unroll
    for(int x=0;x<22;x++){
      float vv = patch[(sg+a)*22 + x][c];
      #pragma unroll
      for(int bq=0;bq<7;bq++){
        int j = x - bq;
        if(j>=0 && j<16) acc[j] += wr[a*7+bq]*vv;
      }
    }
  #pragma unroll
  for(int a=0;a<5;a++)
    #pragma unroll
    for(int x=1;x<21;x++){
      float vv = patch[(sg+a+1)*22 + x][c];
      #pragma unroll
      for(int bq=0;bq<5;bq++){
        int j = x - 1 - bq;
        if(j>=0 && j<16) acc[j] += wr[49+a*5+bq]*vv;
      }
    }
  #pragma unroll
  for(int a=0;a<3;a++)
    #pragma unroll
    for(int x=2;x<20;x++){
      float vv = patch[(sg+a+2)*22 + x][c];
      #pragma unroll
      for(int bq=0;bq<3;bq++){
        int j = x - 2 - bq;
        if(j>=0 && j<16) acc[j] += wr[74+a*3+bq]*vv;
      }
    }
  #pragma unroll
  for(int j=0;j<16;j++)
    Y[(size_t)((ti*16+sg)*128 + tj*16+j)*CDIM + cglob] = acc[j];
}

// ---------------- final LN(row0) + fc2 ----------------
__global__ __launch_bounds__(512) void k_final(const float* __restrict__ A,
    const float* __restrict__ g, const float* __restrict__ b,
    const float* __restrict__ w, const float* __restrict__ bias,
    float* __restrict__ outp){
  __shared__ float red[8];
  int t = threadIdx.x, wv = t >> 6;
  float x = A[t];
  float s = wave_sum(x);
  if((t & 63) == 0) red[wv] = s;
  __syncthreads();
  float mu = 0;
  #pragma unroll
  for(int i=0;i<8;i++) mu += red[i];
  mu *= (1.f/512.f);
  __syncthreads();
  float dx = x - mu;
  s = wave_sum(dx*dx);
  if((t & 63) == 0) red[wv] = s;
  __syncthreads();
  float var = 0;
  #pragma unroll
  for(int i=0;i<8;i++) var += red[i];
  var *= (1.f/512.f);
  float xn = dx * rsqrtf(var + 1e-5f) * g[t] + b[t];
  __syncthreads();
  for(int o=0;o<4;o++){
    s = wave_sum(xn * w[t*4 + o]);
    if((t & 63) == 0) red[wv] = s;
    __syncthreads();
    if(t == 0){
      float r = 0;
      #pragma unroll
      for(int i=0;i<8;i++) r += red[i];
      outp[o] = r + bias[o];
    }
    __syncthreads();
  }
}

extern "C" void kernel_launch(void* const* d_in, const int* in_sizes, int n_in,
                              void* d_out, int out_size, void* d_ws, size_t ws_size,
                              hipStream_t stream) {
  (void)in_sizes; (void)n_in; (void)out_size; (void)ws_size;
  const float* data_x = (const float*)d_in[0];
  const float* fc1_w  = (const float*)d_in[1];
  const float* fc1_b  = (const float*)d_in[2];
  const float* cls_tk = (const float*)d_in[3];
  const float* ng[2]  = {(const float*)d_in[4],  (const float*)d_in[16]};
  const float* nb[2]  = {(const float*)d_in[5],  (const float*)d_in[17]};
  const float* qkvw[2]= {(const float*)d_in[6],  (const float*)d_in[18]};
  const float* outw[2]= {(const float*)d_in[7],  (const float*)d_in[19]};
  const float* outb[2]= {(const float*)d_in[8],  (const float*)d_in[20]};
  const float* resw[2]= {(const float*)d_in[9],  (const float*)d_in[21]};
  const float* w7 = (const float*)d_in[10]; const float* pb7 = (const float*)d_in[11];
  const float* w5 = (const float*)d_in[12]; const float* pb5 = (const float*)d_in[13];
  const float* w3 = (const float*)d_in[14]; const float* pb3 = (const float*)d_in[15];
  const float* norm_g = (const float*)d_in[22];
  const float* norm_b = (const float*)d_in[23];
  const float* fc2_w  = (const float*)d_in[24];
  const float* fc2_b  = (const float*)d_in[25];

  float* ws = (float*)d_ws;
  float* Ab   = ws;
  float* Bb   = Ab + (size_t)TOK*CDIM;
  float* Fb   = Bb + (size_t)TOK*CDIM;
  short* Fbf  = (short*)(Fb + (size_t)NPAD*CDIM);
  short* lnX  = Fbf + (size_t)NPAD*CDIM;
  short* Qb   = lnX + (size_t)NPAD*CDIM;
  short* Kb   = Qb  + (size_t)NPAD*CDIM;
  short* Vb   = Kb  + (size_t)NPAD*CDIM;
  short* dxb  = Vb  + (size_t)NPAD*CDIM;
  float* qlb  = (float*)(dxb + (size_t)16384*1024);
  float* klb  = qlb + NHEAD*NLAND*DHEAD;
  float* a2b  = klb + NHEAD*NLAND*DHEAD;
  float* z0b  = a2b + NHEAD*NLAND*NLAND;
  float* z1b  = z0b + NHEAD*NLAND*NLAND;
  float* Xb_  = z1b + NHEAD*NLAND*NLAND;
  float* Tb_  = Xb_ + NHEAD*NLAND*NLAND;
  float* Ub_  = Tb_ + NHEAD*NLAND*NLAND;
  float* a3vb = Ub_ + NHEAD*NLAND*NLAND;
  float* w2tb = a3vb + NHEAD*NLAND*DHEAD;
  float* denP = w2tb + NHEAD*DHEAD*NLAND;
  float* hmax = denP + NHEAD*NCG*NLAND;
  float* scal = hmax + 8;
  short* fc1T = (short*)(scal + 8);
  short* qkvT0= fc1T + 512*1024;
  short* qkvT1= qkvT0 + 1536*512;
  short* outT0= qkvT1 + 1536*512;
  short* outT1= outT0 + 512*512;
  short* qkvT[2] = {qkvT0, qkvT1};
  short* outT[2] = {outT0, outT1};

  const int HB = NHEAD*NLAND*NLAND;
  short* zb0  = (short*)z0b;  short* zb1  = zb0 + HB;
  short* xb   = (short*)z1b;  short* tb   = xb + HB;
  short* ub   = (short*)Xb_;  short* a2bf = ub + HB;
  float* zf   = Tb_;

  // all 5 weight transposes in one dispatch
  k_transb5<<<dim3(32,48,5), dim3(32,8), 0, stream>>>(
      fc1_w, fc1T, 1024, 512,
      qkvw[0], qkvT0, 512, 1536,
      qkvw[1], qkvT1, 512, 1536,
      outw[0], outT0, 512, 512,
      outw[1], outT1, 512, 512);
  k_f2b<<<8192, 256, 0, stream>>>(data_x, dxb, 16384*1024/8);

  k_copyrow<<<1, 512, 0, stream>>>(Ab, cls_tk);
  k_gemm_g<0><<<dim3(4, 64), 512, 0, stream>>>(dxb, 1024, fc1T, 1024, fc1_b,
                                               Ab + CDIM, nullptr, nullptr, 16384);
  float* base[2]  = {Ab, Bb};
  for(int L=0; L<2; L++){
    k_ln_pad<<<NPAD/4, 256, 0, stream>>>(base[L], ng[L], nb[L], lnX);
    k_gemm_g<1><<<dim3(12, 65), 512, 0, stream>>>(lnX, CDIM, qkvT[L], CDIM, nullptr,
                                                  Qb, Kb, Vb, NPAD);
    k_landmark2<<<2*NHEAD*NLAND, 64, 0, stream>>>(Qb, Kb, qlb, klb);
    k_a2_mfma<<<dim3(4, NHEAD), 256, 0, stream>>>(qlb, klb, a2b, a2bf);
    k_colmax<<<NHEAD, 256, 0, stream>>>(a2b, hmax);
    k_zinit<<<dim3(256, NHEAD), 256, 0, stream>>>(a2b, hmax, zb0);
    short* zc = zb0; short* zn = zb1;
    for(int it=0; it<6; it++){
      k_pgemm<0,0><<<dim3(4,4,NHEAD), 256, 0, stream>>>(a2bf, zc, xb, nullptr, 0.f, 1.f);
      k_pgemm<1,0><<<dim3(4,4,NHEAD), 256, 0, stream>>>(xb, xb, tb, nullptr, 7.f, 1.f);
      k_pgemm<1,0><<<dim3(4,4,NHEAD), 256, 0, stream>>>(xb, tb, ub, nullptr, 15.f, 1.f);
      if(it < 5){
        k_pgemm<1,0><<<dim3(4,4,NHEAD), 256, 0, stream>>>(zc, ub, zn, nullptr, 13.f, 0.25f);
        short* tmp = zc; zc = zn; zn = tmp;
      } else {
        k_pgemm<1,1><<<dim3(4,4,NHEAD), 256, 0, stream>>>(zc, ub, nullptr, zf, 13.f, 0.25f);
      }
    }
    k_a3v_mfma<<<dim3(NHEAD, NCG), 512, 0, stream>>>(qlb, Kb, Vb, Fb, denP);
    k_a3v_comb<<<NHEAD*NLAND, 64, 0, stream>>>(Fb, denP, a3vb);
    k_sgemm2<0,1><<<dim3(1,4,NHEAD), 256, 0, stream>>>(zf, a3vb, w2tb, 256,64,256,
                                                       65536,16384,16384, 0.f, 1.f);
    k_a1_mfma<<<dim3(130, NHEAD), 256, 0, stream>>>(Qb, klb, w2tb, Fbf);
    k_resconv<<<dim3(260, NHEAD), 256, 0, stream>>>(Vb, resw[L], Fbf);
    k_gemm_g<2><<<dim3(4, 65), 512, 0, stream>>>(Fbf + (size_t)PAD0*CDIM, CDIM,
                                                 outT[L], CDIM, outb[L],
                                                 base[L], nullptr, nullptr, TOK);
    if(L == 0){
      k_ppeg2<<<dim3(64, 32), 256, 0, stream>>>(Ab + CDIM, w7, pb7, w5, pb5, w3, pb3,
                                                Bb + CDIM);
      k_copyrow<<<1, 512, 0, stream>>>(Bb, Ab);
    }
  }
  k_final<<<1, 512, 0, stream>>>(Bb, norm_g, norm_b, fc2_w, fc2_b, (float*)d_out);
}